// Round 11
// baseline (279.110 us; speedup 1.0000x reference)
//
#include <hip/hip_runtime.h>
#include <hip/hip_bf16.h>

// GAT-style graph attention. N=50000, E=600000, FEAT=128, H=8, D=16.
// R11: qkv LDS-stages the A tile (64 rows/iter, padded stride kills bank
//      conflicts) -> no 4x redundant A fetch; B frags loaded from fp32 W
//      in-register (convert_w deleted); single-kernel scan via atomic
//      block-base (CSR offset order across blocks is arbitrary).
//      Else R9/R10: dest-CSR, shfl-free sumexp, bf16 wraw, inline rcp.

#define FEAT 128
#define NHEAD 8
#define NPAD 50048     // N rounded up to multiple of 64
#define ASTRIDE 136    // LDS row stride (bf16 elems): breaks 128-stride conflicts

typedef __attribute__((ext_vector_type(8))) short bf16x8;
typedef __attribute__((ext_vector_type(4))) float f32x4;

__device__ __forceinline__ unsigned short f2bf(float f) {
    unsigned u = __float_as_uint(f);
    u += 0x7fffu + ((u >> 16) & 1u);
    return (unsigned short)(u >> 16);
}
__device__ __forceinline__ float bf2f_lo(unsigned u) { return __uint_as_float(u << 16); }
__device__ __forceinline__ float bf2f_hi(unsigned u) { return __uint_as_float(u & 0xffff0000u); }
__device__ __forceinline__ float bfw(unsigned short u) { return __uint_as_float((unsigned)u << 16); }

__device__ __forceinline__ bf16x8 cvt8(float4 f0, float4 f1) {
    bf16x8 t;
    t[0] = (short)f2bf(f0.x); t[1] = (short)f2bf(f0.y);
    t[2] = (short)f2bf(f0.z); t[3] = (short)f2bf(f0.w);
    t[4] = (short)f2bf(f1.x); t[5] = (short)f2bf(f1.y);
    t[6] = (short)f2bf(f1.z); t[7] = (short)f2bf(f1.w);
    return t;
}

// ---- hist: dest-degree histogram ----
__global__ __launch_bounds__(256) void hist_kernel(
    const int* __restrict__ dsts, int* __restrict__ counts, int E)
{
    int e = blockIdx.x * 256 + threadIdx.x;
    if (e < E) atomicAdd(counts + dsts[e], 1);
}

// ---- single-kernel exclusive scan: block-local scan + atomic block base.
//      Offset order across blocks is arbitrary -> still a valid CSR. ----
__global__ __launch_bounds__(256) void scan_kernel(
    const int* __restrict__ counts, int* __restrict__ offsets,
    int* __restrict__ cursor, int* __restrict__ gcursor, int N)
{
    __shared__ int buf[256];
    __shared__ int sbase;
    int t = threadIdx.x, i = blockIdx.x * 256 + t;
    int v = (i < N) ? counts[i] : 0;
    buf[t] = v; __syncthreads();
    int x = v;
    #pragma unroll
    for (int off = 1; off < 256; off <<= 1) {
        int y = (t >= off) ? buf[t - off] : 0;
        __syncthreads();
        x += y; buf[t] = x;
        __syncthreads();
    }
    if (t == 255) sbase = atomicAdd(gcursor, x);   // x == block total at t=255
    __syncthreads();
    if (i < N) {
        int o = x - v + sbase;
        offsets[i] = o;
        cursor[i] = o;
    }
}

// ---- fill dest-CSR: ONE scattered 4B stream ----
__global__ __launch_bounds__(256) void fill_kernel(
    const int* __restrict__ srcs, const int* __restrict__ dsts,
    int* __restrict__ cursor, int* __restrict__ rec, int E)
{
    int e = blockIdx.x * 256 + threadIdx.x;
    if (e < E) {
        int s = srcs[e], d = dsts[e];
        int pd = atomicAdd(cursor + d, 1);
        __builtin_nontemporal_store(s, rec + pd);
    }
}

// ---- QKV MFMA GEMM: LDS-staged A (64 rows/iter), B frags from fp32 W
//      (in-register cvt, persistent), wave owns 32-col strip ----
__global__ __launch_bounds__(256) void qkv_mfma_kernel(
    const float* __restrict__ X,
    const float* __restrict__ Wq, const float* __restrict__ Wk, const float* __restrict__ Wv,
    const float* __restrict__ bq, const float* __restrict__ bk, const float* __restrict__ bv,
    unsigned short* __restrict__ Q, unsigned short* __restrict__ K,
    unsigned short* __restrict__ V, int N, int numIter)
{
    __shared__ unsigned short As[64 * ASTRIDE];
    const int tid = threadIdx.x;
    const int lane = tid & 63;
    const int wave = tid >> 6;
    const int m = lane & 15, quad = lane >> 4;
    const int colbase = wave * 32;

    const float* Wmat[3] = {Wq, Wk, Wv};
    bf16x8 bfr[3][2][4];
    #pragma unroll
    for (int mat = 0; mat < 3; mat++)
        #pragma unroll
        for (int ctl = 0; ctl < 2; ctl++) {
            const float* wrow = Wmat[mat] + (size_t)(colbase + ctl * 16 + m) * FEAT + quad * 8;
            #pragma unroll
            for (int kc = 0; kc < 4; kc++) {
                float4 f0 = *(const float4*)(wrow + kc * 32);
                float4 f1 = *(const float4*)(wrow + kc * 32 + 4);
                bfr[mat][ctl][kc] = cvt8(f0, f1);
            }
        }

    const float* bias_p[3] = {bq, bk, bv};
    float bias[3][2];
    #pragma unroll
    for (int mat = 0; mat < 3; mat++)
        #pragma unroll
        for (int ctl = 0; ctl < 2; ctl++)
            bias[mat][ctl] = bias_p[mat][colbase + ctl * 16 + m];

    unsigned short* outp[3] = {Q, K, V};

    for (int iter = blockIdx.x; iter < numIter; iter += gridDim.x) {
        const int row0 = iter * 64;
        // cooperative stage: 64 rows x 128 cols fp32 -> bf16 LDS (stride 136)
        #pragma unroll
        for (int rep = 0; rep < 8; rep++) {
            int i4 = rep * 256 + tid;            // float4 index, 0..2047
            int r = i4 >> 5;
            int c = (i4 & 31) * 4;
            int gr = row0 + r;
            float4 f = *(const float4*)(X + (size_t)(gr < N ? gr : N - 1) * FEAT + c);
            unsigned lo = (unsigned)f2bf(f.x) | ((unsigned)f2bf(f.y) << 16);
            unsigned hi = (unsigned)f2bf(f.z) | ((unsigned)f2bf(f.w) << 16);
            *(uint2*)(As + r * ASTRIDE + c) = (uint2){lo, hi};
        }
        __syncthreads();

        #pragma unroll
        for (int sub = 0; sub < 4; sub++) {
            const unsigned short* arow = As + (sub * 16 + m) * ASTRIDE + quad * 8;
            bf16x8 a[4];
            #pragma unroll
            for (int kc = 0; kc < 4; kc++) a[kc] = *(const bf16x8*)(arow + kc * 32);
            f32x4 acc[3][2];
            #pragma unroll
            for (int mat = 0; mat < 3; mat++)
                #pragma unroll
                for (int ctl = 0; ctl < 2; ctl++) acc[mat][ctl] = (f32x4){0.f, 0.f, 0.f, 0.f};
            #pragma unroll
            for (int kc = 0; kc < 4; kc++)
                #pragma unroll
                for (int mat = 0; mat < 3; mat++)
                    #pragma unroll
                    for (int ctl = 0; ctl < 2; ctl++)
                        acc[mat][ctl] = __builtin_amdgcn_mfma_f32_16x16x32_bf16(
                            a[kc], bfr[mat][ctl][kc], acc[mat][ctl], 0, 0, 0);
            #pragma unroll
            for (int mat = 0; mat < 3; mat++)
                #pragma unroll
                for (int ctl = 0; ctl < 2; ctl++)
                    #pragma unroll
                    for (int reg = 0; reg < 4; reg++) {
                        int row = row0 + sub * 16 + quad * 4 + reg;
                        if (row < N)
                            outp[mat][(size_t)row * FEAT + colbase + ctl * 16 + m] =
                                f2bf(acc[mat][ctl][reg] + bias[mat][ctl]);
                    }
        }
        __syncthreads();
    }
}

// ---- sumexp: one wave per DEST node, shfl-free (R9) ----
__global__ __launch_bounds__(256) void sumexp_kernel(
    const int* __restrict__ offsets, const int* __restrict__ counts,
    const int* __restrict__ rec,
    const unsigned short* __restrict__ Q, const unsigned short* __restrict__ K,
    unsigned short* __restrict__ wrawb, float* __restrict__ segsum, int N)
{
    int node = blockIdx.x * 4 + (threadIdx.x >> 6);
    if (node >= N) return;
    int lane = threadIdx.x & 63;
    int j = lane >> 3, h = lane & 7;
    int start = offsets[node], deg = counts[node];
    if (deg == 0) return;

    float kf[16];
    {
        const unsigned* kp = (const unsigned*)(K + (size_t)node * FEAT + h * 16);
        #pragma unroll
        for (int i = 0; i < 8; i++) {
            unsigned u = kp[i];
            kf[2 * i]     = bf2f_lo(u);
            kf[2 * i + 1] = bf2f_hi(u);
        }
    }

    for (int j0 = 0; j0 < deg; j0 += 8) {
        int jj = j0 + j;
        bool act = jj < deg;
        int pos = start + (act ? jj : j0);
        int s = rec[pos];
        const unsigned* qp = (const unsigned*)(Q + (size_t)s * FEAT + h * 16);
        uint4 qa = *(const uint4*)qp;
        uint4 qb = *(const uint4*)(qp + 4);
        float p;
        p  = bf2f_lo(qa.x) * kf[0]  + bf2f_hi(qa.x) * kf[1];
        p += bf2f_lo(qa.y) * kf[2]  + bf2f_hi(qa.y) * kf[3];
        p += bf2f_lo(qa.z) * kf[4]  + bf2f_hi(qa.z) * kf[5];
        p += bf2f_lo(qa.w) * kf[6]  + bf2f_hi(qa.w) * kf[7];
        p += bf2f_lo(qb.x) * kf[8]  + bf2f_hi(qb.x) * kf[9];
        p += bf2f_lo(qb.y) * kf[10] + bf2f_hi(qb.y) * kf[11];
        p += bf2f_lo(qb.z) * kf[12] + bf2f_hi(qb.z) * kf[13];
        p += bf2f_lo(qb.w) * kf[14] + bf2f_hi(qb.w) * kf[15];
        float w = __expf(p * 0.25f);
        if (act) {
            wrawb[(size_t)(start + j0) * NHEAD + lane] = f2bf(w);
            atomicAdd(segsum + (size_t)s * NHEAD + h, w);
        }
    }
}

// ---- gather: one wave per dest node; inline v_rcp(segsum[src]) ----
__global__ __launch_bounds__(256) void gather_kernel(
    const int* __restrict__ offsets, const int* __restrict__ counts,
    const int* __restrict__ rec, const unsigned short* __restrict__ wrawb,
    const float* __restrict__ segsum, const unsigned short* __restrict__ V,
    unsigned short* __restrict__ agg, int N)
{
    int node = blockIdx.x * 4 + (threadIdx.x >> 6);
    if (node >= N) return;
    int lane = threadIdx.x & 63;
    int h = lane >> 3;
    int start = offsets[node], deg = counts[node];
    float ax = 0.f, ay = 0.f;
    int j = 0;
    for (; j + 4 <= deg; j += 4) {
        int p = start + j;
        int s0 = rec[p], s1 = rec[p + 1];
        int s2 = rec[p + 2], s3 = rec[p + 3];
        float w0 = bfw(wrawb[(size_t)(p + 0) * NHEAD + h]) *
                   __builtin_amdgcn_rcpf(segsum[(size_t)s0 * NHEAD + h]);
        float w1 = bfw(wrawb[(size_t)(p + 1) * NHEAD + h]) *
                   __builtin_amdgcn_rcpf(segsum[(size_t)s1 * NHEAD + h]);
        float w2 = bfw(wrawb[(size_t)(p + 2) * NHEAD + h]) *
                   __builtin_amdgcn_rcpf(segsum[(size_t)s2 * NHEAD + h]);
        float w3 = bfw(wrawb[(size_t)(p + 3) * NHEAD + h]) *
                   __builtin_amdgcn_rcpf(segsum[(size_t)s3 * NHEAD + h]);
        unsigned v0 = *(const unsigned*)(V + (size_t)s0 * FEAT + lane * 2);
        unsigned v1 = *(const unsigned*)(V + (size_t)s1 * FEAT + lane * 2);
        unsigned v2 = *(const unsigned*)(V + (size_t)s2 * FEAT + lane * 2);
        unsigned v3 = *(const unsigned*)(V + (size_t)s3 * FEAT + lane * 2);
        ax += w0 * bf2f_lo(v0) + w1 * bf2f_lo(v1) + w2 * bf2f_lo(v2) + w3 * bf2f_lo(v3);
        ay += w0 * bf2f_hi(v0) + w1 * bf2f_hi(v1) + w2 * bf2f_hi(v2) + w3 * bf2f_hi(v3);
    }
    for (; j < deg; j++) {
        int p = start + j;
        int s = rec[p];
        float w = bfw(wrawb[(size_t)p * NHEAD + h]) *
                  __builtin_amdgcn_rcpf(segsum[(size_t)s * NHEAD + h]);
        unsigned v = *(const unsigned*)(V + (size_t)s * FEAT + lane * 2);
        ax += w * bf2f_lo(v);
        ay += w * bf2f_hi(v);
    }
    unsigned o = (unsigned)f2bf(ax) | ((unsigned)f2bf(ay) << 16);
    *(unsigned*)(agg + (size_t)node * FEAT + lane * 2) = o;
}

// ---- out MFMA GEMM: B frags from fp32 Wo (in-register cvt), f32 out ----
__global__ __launch_bounds__(256) void out_mfma_kernel(
    const unsigned short* __restrict__ Ab, const float* __restrict__ Wo,
    const float* __restrict__ bo, float* __restrict__ out, int N, int numTiles)
{
    const int lane = threadIdx.x & 63;
    const int wave = threadIdx.x >> 6;
    const int m = lane & 15, quad = lane >> 4;
    const int colbase = wave * 32;

    bf16x8 bfr[2][4];
    #pragma unroll
    for (int ctl = 0; ctl < 2; ctl++) {
        const float* wrow = Wo + (size_t)(colbase + ctl * 16 + m) * FEAT + quad * 8;
        #pragma unroll
        for (int kc = 0; kc < 4; kc++) {
            float4 f0 = *(const float4*)(wrow + kc * 32);
            float4 f1 = *(const float4*)(wrow + kc * 32 + 4);
            bfr[ctl][kc] = cvt8(f0, f1);
        }
    }
    float bias[2];
    #pragma unroll
    for (int ctl = 0; ctl < 2; ctl++) bias[ctl] = bo[colbase + ctl * 16 + m];

    for (int tile = blockIdx.x; tile < numTiles; tile += gridDim.x) {
        const int row0 = tile * 16;
        const unsigned short* arow = Ab + (size_t)(row0 + m) * FEAT + quad * 8;
        bf16x8 a[4];
        #pragma unroll
        for (int kc = 0; kc < 4; kc++) a[kc] = *(const bf16x8*)(arow + kc * 32);
        f32x4 acc[2];
        #pragma unroll
        for (int ctl = 0; ctl < 2; ctl++) acc[ctl] = (f32x4){0.f, 0.f, 0.f, 0.f};
        #pragma unroll
        for (int kc = 0; kc < 4; kc++)
            #pragma unroll
            for (int ctl = 0; ctl < 2; ctl++)
                acc[ctl] = __builtin_amdgcn_mfma_f32_16x16x32_bf16(
                    a[kc], bfr[ctl][kc], acc[ctl], 0, 0, 0);
        #pragma unroll
        for (int ctl = 0; ctl < 2; ctl++)
            #pragma unroll
            for (int reg = 0; reg < 4; reg++) {
                int row = row0 + quad * 4 + reg;
                if (row < N)
                    out[(size_t)row * FEAT + colbase + ctl * 16 + m] = acc[ctl][reg] + bias[ctl];
            }
    }
}

extern "C" void kernel_launch(void* const* d_in, const int* in_sizes, int n_in,
                              void* d_out, int out_size, void* d_ws, size_t ws_size,
                              hipStream_t stream) {
    const float* X  = (const float*)d_in[0];
    const int*   ei = (const int*)d_in[1];
    const float* Wq = (const float*)d_in[2];
    const float* bq = (const float*)d_in[3];
    const float* Wk = (const float*)d_in[4];
    const float* bk = (const float*)d_in[5];
    const float* Wv = (const float*)d_in[6];
    const float* bv = (const float*)d_in[7];
    const float* Wo = (const float*)d_in[8];
    const float* bo = (const float*)d_in[9];
    float* out = (float*)d_out;

    const int N = in_sizes[0] / FEAT;        // 50000
    const int E = in_sizes[1] / 2;           // 600000
    const int* srcs = ei;
    const int* dsts = ei + E;
    const size_t NF2 = (size_t)NPAD * FEAT * 2;

    char* w = (char*)d_ws;
    unsigned short* Qb = (unsigned short*)w;  w += NF2;
    unsigned short* Kb = (unsigned short*)w;  w += NF2;
    unsigned short* Vb = (unsigned short*)w;  w += NF2;
    unsigned short* Ab = (unsigned short*)w;  w += NF2;
    unsigned short* wrawb = (unsigned short*)w; w += (size_t)E * NHEAD * 2;  // bf16
    float* segsum      = (float*)w;           w += (size_t)N * NHEAD * 4;  // zeroed
    int* counts        = (int*)w;             w += (size_t)N * 4;          // zeroed (contig)
    int* gcursor       = (int*)w;             w += 4;                      // zeroed (contig)
    int* offsets       = (int*)w;             w += (size_t)N * 4;
    int* cursor        = (int*)w;             w += (size_t)N * 4;
    int* rec           = (int*)w;             w += (size_t)E * 4;

    // zero segsum + counts + gcursor (contiguous)
    hipMemsetAsync(segsum, 0, (size_t)N * NHEAD * 4 + (size_t)N * 4 + 4, stream);

    int e_blocks = (E + 255) / 256;          // 2344
    hist_kernel<<<e_blocks, 256, 0, stream>>>(dsts, counts, E);

    int NB = (N + 255) / 256;   // 196
    scan_kernel<<<NB, 256, 0, stream>>>(counts, offsets, cursor, gcursor, N);

    fill_kernel<<<e_blocks, 256, 0, stream>>>(srcs, dsts, cursor, rec, E);

    int numIter = NPAD / 64;    // 782
    qkv_mfma_kernel<<<391, 256, 0, stream>>>(
        X, Wq, Wk, Wv, bq, bk, bv, Qb, Kb, Vb, N, numIter);

    int node_blocks = (N + 3) / 4;
    sumexp_kernel<<<node_blocks, 256, 0, stream>>>(
        offsets, counts, rec, Qb, Kb, wrawb, segsum, N);

    gather_kernel<<<node_blocks, 256, 0, stream>>>(
        offsets, counts, rec, wrawb, segsum, Vb, Ab, N);

    int numTiles = NPAD / 16;   // 3128
    out_mfma_kernel<<<782, 256, 0, stream>>>(Ab, Wo, bo, out, N, numTiles);
}